// Round 8
// baseline (357.240 us; speedup 1.0000x reference)
//
#include <hip/hip_runtime.h>
#include <stdint.h>

typedef unsigned short ushort_t;
typedef _Float16 f16x8 __attribute__((ext_vector_type(8)));
typedef float f32x4 __attribute__((ext_vector_type(4)));
typedef float f32x16 __attribute__((ext_vector_type(16)));
typedef int   i32x4 __attribute__((ext_vector_type(4)));
typedef int   i32x16 __attribute__((ext_vector_type(16)));
typedef unsigned int uint4v __attribute__((ext_vector_type(4)));

#define HW_ 16384
#define MFMAH  __builtin_amdgcn_mfma_f32_32x32x16_f16
#define MFMAI8 __builtin_amdgcn_mfma_i32_32x32x32_i8
#define C_CORR (1.0f/16777216.0f)   // 2^-24: Al8(2^15)*Wh8(2^9) and Ah8(2^4)*Wl8(2^20)

__device__ __forceinline__ ushort_t f2h_bits(float f){
  union { _Float16 h; ushort_t u; } c; c.h = (_Float16)f; return c.u;
}
__device__ __forceinline__ float h_bits2f(ushort_t u){
  union { _Float16 h; ushort_t u; } c; c.u = u; return (float)c.h;
}
__device__ __forceinline__ int clamp8(int v){ return min(max(v,-127),127); }

// ---------------------------------------------------------------------------
// WpH (f16, ushort bits): offset ((conv*2+mh)*36 + ks16)*512 + lane*8 + j
//   conv 0=Ws 1=Wx 2=Wy; co = mh*32+(lane&31); tap = ks16>>2;
//   ci = (ks16&3)*16 + (lane>>5)*8 + j.
// WpC (i8 dwords): dword ((g*2+mh)*18 + ks32)*256 + lane*4 + j4
//   g 0=Wh8x 1=Wh8y 2=Wl8x 3=Wl8y; tap = ks32>>1;
//   ci = (ks32&1)*32 + (lane>>5)*16 + j4*4 + bb.
// ---------------------------------------------------------------------------
__global__ __launch_bounds__(256) void k_repack(
    const float* __restrict__ Ws, const float* __restrict__ Wx,
    const float* __restrict__ Wy,
    ushort_t* __restrict__ WpH, unsigned int* __restrict__ WpC){
  int e = blockIdx.x*256 + threadIdx.x;
  if (e < 110592){
    int j = e & 7; int lane = (e >> 3) & 63; int rest = e >> 9;
    int ks = rest % 36; int cm = rest / 36;
    int conv = cm >> 1; int mh = cm & 1;
    int co = mh*32 + (lane & 31);
    int tap = ks >> 2;
    int ci = (ks & 3)*16 + ((lane >> 5) & 1)*8 + j;
    const float* src = (conv==0) ? Ws : (conv==1) ? Wx : Wy;
    WpH[e] = f2h_bits(src[(co*64 + ci)*9 + tap]);
  } else if (e < 110592 + 36864){
    int d = e - 110592;
    int j4 = d & 3; int lane = (d >> 2) & 63; int rest = d >> 8;
    int ks = rest % 18; int gm = rest / 18;
    int g = gm >> 1; int mh = gm & 1;
    int co = mh*32 + (lane & 31);
    int tap = ks >> 1;
    const float* src = (g==0 || g==2) ? Wx : Wy;
    unsigned dd = 0;
    #pragma unroll
    for (int bb=0; bb<4; bb++){
      int ci = (ks & 1)*32 + ((lane >> 5) & 1)*16 + j4*4 + bb;
      float w = src[(co*64 + ci)*9 + tap];
      int v;
      if (g < 2){
        v = clamp8((int)rintf(w*512.f));
      } else {
        float wl = w - h_bits2f(f2h_bits(w));
        v = clamp8((int)rintf(wl*1048576.f));
      }
      dd |= ((unsigned)(v & 255)) << (bb*8);
    }
    WpC[d] = dd;
  }
}

// ---------------------------------------------------------------------------
// Fused conv: score + gx/gy. Hi path f16 MFMA; corrections via i8 MFMA
// (joint scale 2^24). WG tile: 2 h-rows x 64 w; wave (mh, ph).
// LDS B: BH f16 [4r][66 w1][64 ci] oct-swizzled o^(w1&7);
//        BAl/BAh i8 [4r][66][64], 16B-chunk slot (q+(w1>>1))&3.
// Grid 2048 XCD-swizzled: all WGs of batch b on XCD b&7.
// ---------------------------------------------------------------------------
__global__ __launch_bounds__(256, 2) void k_conv_all(
    const float* __restrict__ x,
    const ushort_t* __restrict__ WpH, const unsigned int* __restrict__ WpC,
    const float* __restrict__ bs, const float* __restrict__ bx,
    const float* __restrict__ by,
    ushort_t* __restrict__ score, unsigned int* __restrict__ coords){
  int bid = blockIdx.x;
  int idx = bid >> 3;
  int b = (bid & 7) + 8*(idx >> 7);
  int rest = idx & 127;
  int h0 = (rest >> 1)*2;
  int wq = (rest & 1)*64;
  int t = threadIdx.x; int lane = t & 63; int wid = t >> 6;
  int n = lane & 31; int kh = lane >> 5;
  __shared__ __align__(16) _Float16 BH[16896];
  __shared__ __align__(16) char BAl[16896];
  __shared__ __align__(16) char BAh[16896];

  // ---- staging: 1056 items of 16 ci; f16-hi + Al8 + Ah8 in registers ----
  const float* xb = x + (size_t)b*64*HW_;
  #pragma unroll
  for (int it=0; it<5; it++){
    int f = it*256 + t;
    if (f < 1056){
      int r = f/264; int rem = f - r*264; int q = rem/66; int w1 = rem - q*66;
      int y = h0 + r - 1; int w = wq + w1 - 1;
      f16x8 h0v = {0,0,0,0,0,0,0,0}, h1v = {0,0,0,0,0,0,0,0};
      unsigned alb[4] = {0,0,0,0}, ahb[4] = {0,0,0,0};
      if (((unsigned)y < 128u) & ((unsigned)w < 128u)){
        const float* p = xb + (size_t)(q*16)*HW_ + y*128 + w;
        #pragma unroll
        for (int j=0; j<16; j++){
          float v = p[(size_t)j*HW_];
          _Float16 hv = (_Float16)v;
          float al = v - (float)hv;
          int a8 = clamp8((int)rintf(al*32768.f));
          int x8 = clamp8((int)rintf(v*16.f));
          if (j < 8) h0v[j] = hv; else h1v[j-8] = hv;
          alb[j>>2] |= ((unsigned)(a8 & 255)) << ((j&3)*8);
          ahb[j>>2] |= ((unsigned)(x8 & 255)) << ((j&3)*8);
        }
      }
      int base = (r*66 + w1)*64;       // element/byte row base (64/row)
      int sw = w1 & 7;
      *(f16x8*)&BH[base + (((2*q)   ^ sw) << 3)] = h0v;
      *(f16x8*)&BH[base + (((2*q+1) ^ sw) << 3)] = h1v;
      int islot = ((q + (w1 >> 1)) & 3) << 4;
      i32x4 av = {(int)alb[0],(int)alb[1],(int)alb[2],(int)alb[3]};
      i32x4 hv2 = {(int)ahb[0],(int)ahb[1],(int)ahb[2],(int)ahb[3]};
      *(i32x4*)&BAl[base + islot] = av;
      *(i32x4*)&BAh[base + islot] = hv2;
    }
  }
  __syncthreads();

  int mh = wid & 1;      // co half
  int ph = wid >> 1;     // h row within tile

  f32x16 acc_s[2], gxh[2], gyh[2];
  i32x16 cx[2], cy[2];
  #pragma unroll
  for (int ni=0; ni<2; ni++){
    #pragma unroll
    for (int r2=0; r2<16; r2++){
      acc_s[ni][r2]=0.f; gxh[ni][r2]=0.f; gyh[ni][r2]=0.f;
      cx[ni][r2]=0; cy[ni][r2]=0;
    }
  }

  const ushort_t* aS = WpH + ((0*2+mh)*36)*512 + lane*8;
  const ushort_t* aX = WpH + ((1*2+mh)*36)*512 + lane*8;
  const ushort_t* aY = WpH + ((2*2+mh)*36)*512 + lane*8;
  const char* cWhx = (const char*)WpC + (((0*2+mh)*18)*64 + lane)*16;
  const char* cWhy = (const char*)WpC + (((1*2+mh)*18)*64 + lane)*16;
  const char* cWlx = (const char*)WpC + (((2*2+mh)*18)*64 + lane)*16;
  const char* cWly = (const char*)WpC + (((3*2+mh)*18)*64 + lane)*16;

  #pragma unroll
  for (int tap=0; tap<9; tap++){
    int rb = tap/3; int dw = tap - rb*3 - 1;
    int row = rb + ph;
    #pragma unroll
    for (int qp=0; qp<2; qp++){
      int ksA = tap*4 + qp*2;
      int ks32 = tap*2 + qp;
      f16x8 sA = *(const f16x8*)&aS[ksA*512];
      f16x8 sB = *(const f16x8*)&aS[(ksA+1)*512];
      f16x8 xA = *(const f16x8*)&aX[ksA*512];
      f16x8 xB = *(const f16x8*)&aX[(ksA+1)*512];
      f16x8 yA = *(const f16x8*)&aY[ksA*512];
      f16x8 yB = *(const f16x8*)&aY[(ksA+1)*512];
      i32x4 whx = *(const i32x4*)&cWhx[ks32*1024];
      i32x4 why = *(const i32x4*)&cWhy[ks32*1024];
      i32x4 wlx = *(const i32x4*)&cWlx[ks32*1024];
      i32x4 wly = *(const i32x4*)&cWly[ks32*1024];
      int oA = qp*4 + kh;
      int oB = qp*4 + 2 + kh;
      int q2 = qp*2 + kh;
      #pragma unroll
      for (int ni=0; ni<2; ni++){
        int w1 = ni*32 + n + dw + 1;
        int rowb = (row*66 + w1)*64;
        int sw = w1 & 7;
        f16x8 bA = *(const f16x8*)&BH[rowb + ((oA ^ sw) << 3)];
        f16x8 bB = *(const f16x8*)&BH[rowb + ((oB ^ sw) << 3)];
        int islot = ((q2 + (w1 >> 1)) & 3) << 4;
        i32x4 bal = *(const i32x4*)&BAl[rowb + islot];
        i32x4 bah = *(const i32x4*)&BAh[rowb + islot];
        acc_s[ni] = MFMAH(sA, bA, acc_s[ni], 0,0,0);
        gxh[ni]   = MFMAH(xA, bA, gxh[ni],   0,0,0);
        gyh[ni]   = MFMAH(yA, bA, gyh[ni],   0,0,0);
        acc_s[ni] = MFMAH(sB, bB, acc_s[ni], 0,0,0);
        gxh[ni]   = MFMAH(xB, bB, gxh[ni],   0,0,0);
        gyh[ni]   = MFMAH(yB, bB, gyh[ni],   0,0,0);
        cx[ni] = MFMAI8(whx, bal, cx[ni], 0,0,0);
        cx[ni] = MFMAI8(wlx, bah, cx[ni], 0,0,0);
        cy[ni] = MFMAI8(why, bal, cy[ni], 0,0,0);
        cy[ni] = MFMAI8(wly, bah, cy[ni], 0,0,0);
      }
    }
  }

  // epilogue: score f16 + packed u16 coords (step 1/480 px, clamp [-2,129])
  int h = h0 + ph;
  #pragma unroll
  for (int ni=0; ni<2; ni++){
    int w = wq + ni*32 + n;
    ushort_t*     sb = score  + (size_t)b*64*HW_ + h*128 + w;
    unsigned int* cb = coords + (size_t)b*64*HW_ + h*128 + w;
    #pragma unroll
    for (int reg=0; reg<16; reg++){
      int col = mh*32 + (reg & 3) + 8*(reg >> 2) + 4*kh;
      float sv = acc_s[ni][reg] + bs[col];
      float gx = gxh[ni][reg] + (float)cx[ni][reg]*C_CORR + bx[col];
      float gy = gyh[ni][reg] + (float)cy[ni][reg]*C_CORR + by[col];
      sb[(size_t)col*HW_] = f2h_bits(sv);
      float ix = fminf(fmaxf((gx + 1.f)*64.f - 0.5f, -2.f), 129.f);
      float iy = fminf(fmaxf((gy + 1.f)*64.f - 0.5f, -2.f), 129.f);
      unsigned ux = (unsigned)rintf((ix + 2.f)*480.f);
      unsigned uy = (unsigned)rintf((iy + 2.f)*480.f);
      cb[(size_t)col*HW_] = ux | (uy << 16);
    }
  }
}

// ---------------------------------------------------------------------------
// Sampler: one WG per (b,co); f16 score plane in LDS; coords/out streamed.
// Grid 1024 XCD-swizzled (matches conv's b->XCD mapping, L2-hot reads).
// ---------------------------------------------------------------------------
__global__ __launch_bounds__(256, 4) void k_sample(
    const ushort_t* __restrict__ score, const unsigned int* __restrict__ coords,
    float* __restrict__ out){
  int bid = blockIdx.x;
  int idx = bid >> 3;
  int b  = (bid & 7) + 8*(idx >> 6);
  int co = idx & 63;
  int t = threadIdx.x;
  __shared__ __align__(16) ushort_t SC[128*136];

  const ushort_t* sp = score + (size_t)(b*64 + co)*HW_;
  #pragma unroll
  for (int i=0;i<8;i++){
    int c = i*256 + t;
    int y = c >> 4; int xg = (c & 15)*8;
    *(f16x8*)&SC[y*136 + xg] = *(const f16x8*)(sp + c*8);
  }
  __syncthreads();

  const unsigned int* cp = coords + (size_t)(b*64 + co)*HW_;
  float* op = out + (size_t)(b*64 + co)*HW_;
  uint4v ca = *(const uint4v*)(cp + t*8);
  uint4v cb2 = *(const uint4v*)(cp + t*8 + 4);
  #pragma unroll 1
  for (int k=0;k<8;k++){
    int px = (k*256 + t)*8;
    uint4v na, nb;
    if (k < 7){
      na = *(const uint4v*)(cp + px + 2048);
      nb = *(const uint4v*)(cp + px + 2052);
    }
    float r[8];
    #pragma unroll
    for (int j=0;j<8;j++){
      unsigned u = (j < 4) ? ca[j] : cb2[j-4];
      float ix = (float)(u & 0xffffu)*(1.0f/480.0f) - 2.0f;
      float iy = (float)(u >> 16)   *(1.0f/480.0f) - 2.0f;
      float x0f = floorf(ix), y0f = floorf(iy);
      int x0 = (int)x0f, y0 = (int)y0f;
      float wx1 = ix - x0f, wy1 = iy - y0f;
      float wx0 = 1.f - wx1, wy0 = 1.f - wy1;
      int x0c = min(max(x0,0),127), x1c = min(max(x0+1,0),127);
      int y0c = min(max(y0,0),127), y1c = min(max(y0+1,0),127);
      bool vx0 = (unsigned)x0     < 128u, vx1 = (unsigned)(x0+1) < 128u;
      bool vy0 = (unsigned)y0     < 128u, vy1 = (unsigned)(y0+1) < 128u;
      float v00 = (vy0 && vx0) ? h_bits2f(SC[y0c*136 + x0c]) : 0.f;
      float v01 = (vy0 && vx1) ? h_bits2f(SC[y0c*136 + x1c]) : 0.f;
      float v10 = (vy1 && vx0) ? h_bits2f(SC[y1c*136 + x0c]) : 0.f;
      float v11 = (vy1 && vx1) ? h_bits2f(SC[y1c*136 + x1c]) : 0.f;
      r[j] = v00*(wy0*wx0) + v01*(wy0*wx1) + v10*(wy1*wx0) + v11*(wy1*wx1);
    }
    f32x4 r0 = {r[0],r[1],r[2],r[3]};
    f32x4 r1 = {r[4],r[5],r[6],r[7]};
    *(f32x4*)(op + px)     = r0;
    *(f32x4*)(op + px + 4) = r1;
    ca = na; cb2 = nb;
  }
}

// ---------------------------------------------------------------------------
extern "C" void kernel_launch(void* const* d_in, const int* in_sizes, int n_in,
                              void* d_out, int out_size, void* d_ws, size_t ws_size,
                              hipStream_t stream){
  const float* x  = (const float*)d_in[0];
  const float* Ws = (const float*)d_in[1];
  const float* bs = (const float*)d_in[2];
  const float* Wx = (const float*)d_in[3];
  const float* bx = (const float*)d_in[4];
  const float* Wy = (const float*)d_in[5];
  const float* by = (const float*)d_in[6];
  float* out = (float*)d_out;
  ushort_t* ws  = (ushort_t*)d_ws;
  ushort_t*     score  = ws;                                   // 33.5 MB f16
  unsigned int* coords = (unsigned int*)(ws + 16777216);       // 67.1 MB u32
  ushort_t*     WpH    = ws + 50331648;                        // 221 KB
  unsigned int* WpC    = (unsigned int*)(ws + 50331648 + 110592); // 147 KB

  k_repack  <<<dim3(576),  256, 0, stream>>>(Ws, Wx, Wy, WpH, WpC);
  k_conv_all<<<dim3(2048), 256, 0, stream>>>(x, WpH, WpC, bs, bx, by, score, coords);
  k_sample  <<<dim3(1024), 256, 0, stream>>>(score, coords, out);
}

// Round 9
// 285.308 us; speedup vs baseline: 1.2521x; 1.2521x over previous
//
#include <hip/hip_runtime.h>
#include <stdint.h>

typedef unsigned short ushort_t;
typedef _Float16 f16x8 __attribute__((ext_vector_type(8)));
typedef float f32x4 __attribute__((ext_vector_type(4)));
typedef float f32x16 __attribute__((ext_vector_type(16)));
typedef int   i32x4 __attribute__((ext_vector_type(4)));
typedef int   i32x16 __attribute__((ext_vector_type(16)));
typedef unsigned int uint4v __attribute__((ext_vector_type(4)));

#define HW_ 16384
#define MFMAH  __builtin_amdgcn_mfma_f32_32x32x16_f16
#define MFMAI8 __builtin_amdgcn_mfma_i32_32x32x32_i8
#define C_CORR (1.0f/16777216.0f)   // 2^-24: Al8(2^15)*Wh8(2^9) and Ah8(2^4)*Wl8(2^20)

__device__ __forceinline__ ushort_t f2h_bits(float f){
  union { _Float16 h; ushort_t u; } c; c.h = (_Float16)f; return c.u;
}
__device__ __forceinline__ float h_bits2f(ushort_t u){
  union { _Float16 h; ushort_t u; } c; c.u = u; return (float)c.h;
}
__device__ __forceinline__ int clamp8(int v){ return min(max(v,-127),127); }

// ---------------------------------------------------------------------------
// WpH (f16 bits): ((conv*2+mh)*36 + ks16)*512 + lane*8 + j
//   conv 0=Ws 1=Wx 2=Wy; co = mh*32+(lane&31); tap = ks16>>2;
//   ci = (ks16&3)*16 + (lane>>5)*8 + j.
// WpC (i8 dwords): ((g*2+mh)*18 + ks32)*256 + lane*4 + j4
//   g 0=Wh8x 1=Wh8y 2=Wl8x 3=Wl8y; tap = ks32>>1;
//   ci = (ks32&1)*32 + (lane>>5)*16 + j4*4 + bb.
// ---------------------------------------------------------------------------
__global__ __launch_bounds__(256) void k_repack(
    const float* __restrict__ Ws, const float* __restrict__ Wx,
    const float* __restrict__ Wy,
    ushort_t* __restrict__ WpH, unsigned int* __restrict__ WpC){
  int e = blockIdx.x*256 + threadIdx.x;
  if (e < 110592){
    int j = e & 7; int lane = (e >> 3) & 63; int rest = e >> 9;
    int ks = rest % 36; int cm = rest / 36;
    int conv = cm >> 1; int mh = cm & 1;
    int co = mh*32 + (lane & 31);
    int tap = ks >> 2;
    int ci = (ks & 3)*16 + ((lane >> 5) & 1)*8 + j;
    const float* src = (conv==0) ? Ws : (conv==1) ? Wx : Wy;
    WpH[e] = f2h_bits(src[(co*64 + ci)*9 + tap]);
  } else if (e < 110592 + 36864){
    int d = e - 110592;
    int j4 = d & 3; int lane = (d >> 2) & 63; int rest = d >> 8;
    int ks = rest % 18; int gm = rest / 18;
    int g = gm >> 1; int mh = gm & 1;
    int co = mh*32 + (lane & 31);
    int tap = ks >> 1;
    const float* src = (g==0 || g==2) ? Wx : Wy;
    unsigned dd = 0;
    #pragma unroll
    for (int bb=0; bb<4; bb++){
      int ci = (ks & 1)*32 + ((lane >> 5) & 1)*16 + j4*4 + bb;
      float w = src[(co*64 + ci)*9 + tap];
      int v;
      if (g < 2){
        v = clamp8((int)rintf(w*512.f));
      } else {
        float wl = w - h_bits2f(f2h_bits(w));
        v = clamp8((int)rintf(wl*1048576.f));
      }
      dd |= ((unsigned)(v & 255)) << (bb*8);
    }
    WpC[d] = dd;
  }
}

// ---------------------------------------------------------------------------
// Fused conv: score + gx/gy. Hi path f16 MFMA; corrections via 2 i8 MFMA
// (joint scale 2^24). WG tile: 2 h-rows x 32 w; wave (mh, ph), N=32.
// 80 accumulator VGPRs/wave -> no spill (R8 regression root cause).
// LDS: BH f16 [4r][34 w1][64ci] oct-swizzle o^(w1&7);
//      BAl/BAh i8 same grid, 16B-chunk slot (q+(w1>>1))&3.  34.8 KB total.
// Grid 4096 XCD-swizzled: all WGs of batch b on XCD b&7.
// ---------------------------------------------------------------------------
__global__ __launch_bounds__(256, 2) void k_conv_all(
    const float* __restrict__ x,
    const ushort_t* __restrict__ WpH, const unsigned int* __restrict__ WpC,
    const float* __restrict__ bs, const float* __restrict__ bx,
    const float* __restrict__ by,
    ushort_t* __restrict__ score, unsigned int* __restrict__ coords){
  int bid = blockIdx.x;
  int idx = bid >> 3;
  int b = (bid & 7) + 8*(idx >> 8);
  int rest = idx & 255;
  int h0 = (rest >> 2)*2;
  int wq = (rest & 3)*32;
  int t = threadIdx.x; int lane = t & 63; int wid = t >> 6;
  int n = lane & 31; int kh = lane >> 5;
  __shared__ __align__(16) _Float16 BH[4*34*64];   // 17408 B
  __shared__ __align__(16) char BAl[4*34*64];      //  8704 B
  __shared__ __align__(16) char BAh[4*34*64];      //  8704 B

  // ---- staging: 544 items of 16 ci; f16-hi + Al8 + Ah8 in registers ----
  const float* xb = x + (size_t)b*64*HW_;
  #pragma unroll
  for (int it=0; it<3; it++){
    int f = it*256 + t;
    if (f < 544){
      int r = f/136; int rem = f - r*136; int q = rem/34; int w1 = rem - q*34;
      int y = h0 + r - 1; int w = wq + w1 - 1;
      f16x8 h0v = {0,0,0,0,0,0,0,0}, h1v = {0,0,0,0,0,0,0,0};
      unsigned alb[4] = {0,0,0,0}, ahb[4] = {0,0,0,0};
      if (((unsigned)y < 128u) & ((unsigned)w < 128u)){
        const float* p = xb + (size_t)(q*16)*HW_ + y*128 + w;
        #pragma unroll
        for (int j=0; j<16; j++){
          float v = p[(size_t)j*HW_];
          _Float16 hv = (_Float16)v;
          float al = v - (float)hv;
          int a8 = clamp8((int)rintf(al*32768.f));
          int x8 = clamp8((int)rintf(v*16.f));
          if (j < 8) h0v[j] = hv; else h1v[j-8] = hv;
          alb[j>>2] |= ((unsigned)(a8 & 255)) << ((j&3)*8);
          ahb[j>>2] |= ((unsigned)(x8 & 255)) << ((j&3)*8);
        }
      }
      int base = (r*34 + w1)*64;
      int sw = w1 & 7;
      *(f16x8*)&BH[base + (((2*q)   ^ sw) << 3)] = h0v;
      *(f16x8*)&BH[base + (((2*q+1) ^ sw) << 3)] = h1v;
      int islot = ((q + (w1 >> 1)) & 3) << 4;
      i32x4 av  = {(int)alb[0],(int)alb[1],(int)alb[2],(int)alb[3]};
      i32x4 hv2 = {(int)ahb[0],(int)ahb[1],(int)ahb[2],(int)ahb[3]};
      *(i32x4*)&BAl[base + islot] = av;
      *(i32x4*)&BAh[base + islot] = hv2;
    }
  }
  __syncthreads();

  int mh = wid & 1;      // co half
  int ph = wid >> 1;     // h row within tile

  f32x16 acc_s, acc_gx, acc_gy;
  i32x16 c_x, c_y;
  #pragma unroll
  for (int r2=0; r2<16; r2++){
    acc_s[r2]=0.f; acc_gx[r2]=0.f; acc_gy[r2]=0.f; c_x[r2]=0; c_y[r2]=0;
  }

  const ushort_t* aS = WpH + ((0*2+mh)*36)*512 + lane*8;
  const ushort_t* aX = WpH + ((1*2+mh)*36)*512 + lane*8;
  const ushort_t* aY = WpH + ((2*2+mh)*36)*512 + lane*8;
  const char* cWhx = (const char*)WpC + (((0*2+mh)*18)*64 + lane)*16;
  const char* cWhy = (const char*)WpC + (((1*2+mh)*18)*64 + lane)*16;
  const char* cWlx = (const char*)WpC + (((2*2+mh)*18)*64 + lane)*16;
  const char* cWly = (const char*)WpC + (((3*2+mh)*18)*64 + lane)*16;

  #pragma unroll
  for (int tap=0; tap<9; tap++){
    int rb = tap/3; int dw = tap - rb*3 - 1;
    int row = rb + ph;
    int w1 = n + dw + 1;                    // 0..33
    int rowb = (row*34 + w1)*64;
    int sw = w1 & 7;
    int islotbase = (w1 >> 1);
    #pragma unroll
    for (int qp=0; qp<2; qp++){
      int ksA  = tap*4 + qp*2;
      int ks32 = tap*2 + qp;
      f16x8 sA = *(const f16x8*)&aS[ksA*512];
      f16x8 sB = *(const f16x8*)&aS[(ksA+1)*512];
      f16x8 xA = *(const f16x8*)&aX[ksA*512];
      f16x8 xB = *(const f16x8*)&aX[(ksA+1)*512];
      f16x8 yA = *(const f16x8*)&aY[ksA*512];
      f16x8 yB = *(const f16x8*)&aY[(ksA+1)*512];
      i32x4 whx = *(const i32x4*)&cWhx[ks32*1024];
      i32x4 why = *(const i32x4*)&cWhy[ks32*1024];
      i32x4 wlx = *(const i32x4*)&cWlx[ks32*1024];
      i32x4 wly = *(const i32x4*)&cWly[ks32*1024];
      f16x8 bA = *(const f16x8*)&BH[rowb + (((qp*4 + kh)     ^ sw) << 3)];
      f16x8 bB = *(const f16x8*)&BH[rowb + (((qp*4 + 2 + kh) ^ sw) << 3)];
      int islot = (((qp*2 + kh) + islotbase) & 3) << 4;
      i32x4 bal = *(const i32x4*)&BAl[rowb + islot];
      i32x4 bah = *(const i32x4*)&BAh[rowb + islot];
      acc_s  = MFMAH(sA, bA, acc_s,  0,0,0);
      acc_gx = MFMAH(xA, bA, acc_gx, 0,0,0);
      acc_gy = MFMAH(yA, bA, acc_gy, 0,0,0);
      acc_s  = MFMAH(sB, bB, acc_s,  0,0,0);
      acc_gx = MFMAH(xB, bB, acc_gx, 0,0,0);
      acc_gy = MFMAH(yB, bB, acc_gy, 0,0,0);
      c_x = MFMAI8(whx, bal, c_x, 0,0,0);
      c_x = MFMAI8(wlx, bah, c_x, 0,0,0);
      c_y = MFMAI8(why, bal, c_y, 0,0,0);
      c_y = MFMAI8(wly, bah, c_y, 0,0,0);
    }
  }

  // epilogue: score f16 + packed u16 coords (step 1/480 px, clamp [-2,129])
  int h = h0 + ph;
  int w = wq + n;
  ushort_t*     sb = score  + (size_t)b*64*HW_ + h*128 + w;
  unsigned int* cb = coords + (size_t)b*64*HW_ + h*128 + w;
  #pragma unroll
  for (int reg=0; reg<16; reg++){
    int col = mh*32 + (reg & 3) + 8*(reg >> 2) + 4*kh;
    float sv = acc_s[reg] + bs[col];
    float gx = acc_gx[reg] + (float)c_x[reg]*C_CORR + bx[col];
    float gy = acc_gy[reg] + (float)c_y[reg]*C_CORR + by[col];
    sb[(size_t)col*HW_] = f2h_bits(sv);
    float ix = fminf(fmaxf((gx + 1.f)*64.f - 0.5f, -2.f), 129.f);
    float iy = fminf(fmaxf((gy + 1.f)*64.f - 0.5f, -2.f), 129.f);
    unsigned ux = (unsigned)rintf((ix + 2.f)*480.f);
    unsigned uy = (unsigned)rintf((iy + 2.f)*480.f);
    cb[(size_t)col*HW_] = ux | (uy << 16);
  }
}

// ---------------------------------------------------------------------------
// Sampler: one WG per (b,co); f16 score plane in LDS; coords/out streamed.
// Grid 1024 XCD-swizzled (matches conv's b->XCD mapping, L2-hot reads).
// ---------------------------------------------------------------------------
__global__ __launch_bounds__(256, 4) void k_sample(
    const ushort_t* __restrict__ score, const unsigned int* __restrict__ coords,
    float* __restrict__ out){
  int bid = blockIdx.x;
  int idx = bid >> 3;
  int b  = (bid & 7) + 8*(idx >> 6);
  int co = idx & 63;
  int t = threadIdx.x;
  __shared__ __align__(16) ushort_t SC[128*136];

  const ushort_t* sp = score + (size_t)(b*64 + co)*HW_;
  #pragma unroll
  for (int i=0;i<8;i++){
    int c = i*256 + t;
    int y = c >> 4; int xg = (c & 15)*8;
    *(f16x8*)&SC[y*136 + xg] = *(const f16x8*)(sp + c*8);
  }
  __syncthreads();

  const unsigned int* cp = coords + (size_t)(b*64 + co)*HW_;
  float* op = out + (size_t)(b*64 + co)*HW_;
  uint4v ca = *(const uint4v*)(cp + t*8);
  uint4v cb2 = *(const uint4v*)(cp + t*8 + 4);
  #pragma unroll 1
  for (int k=0;k<8;k++){
    int px = (k*256 + t)*8;
    uint4v na, nb;
    if (k < 7){
      na = *(const uint4v*)(cp + px + 2048);
      nb = *(const uint4v*)(cp + px + 2052);
    }
    float r[8];
    #pragma unroll
    for (int j=0;j<8;j++){
      unsigned u = (j < 4) ? ca[j] : cb2[j-4];
      float ix = (float)(u & 0xffffu)*(1.0f/480.0f) - 2.0f;
      float iy = (float)(u >> 16)   *(1.0f/480.0f) - 2.0f;
      float x0f = floorf(ix), y0f = floorf(iy);
      int x0 = (int)x0f, y0 = (int)y0f;
      float wx1 = ix - x0f, wy1 = iy - y0f;
      float wx0 = 1.f - wx1, wy0 = 1.f - wy1;
      int x0c = min(max(x0,0),127), x1c = min(max(x0+1,0),127);
      int y0c = min(max(y0,0),127), y1c = min(max(y0+1,0),127);
      bool vx0 = (unsigned)x0     < 128u, vx1 = (unsigned)(x0+1) < 128u;
      bool vy0 = (unsigned)y0     < 128u, vy1 = (unsigned)(y0+1) < 128u;
      float v00 = (vy0 && vx0) ? h_bits2f(SC[y0c*136 + x0c]) : 0.f;
      float v01 = (vy0 && vx1) ? h_bits2f(SC[y0c*136 + x1c]) : 0.f;
      float v10 = (vy1 && vx0) ? h_bits2f(SC[y1c*136 + x0c]) : 0.f;
      float v11 = (vy1 && vx1) ? h_bits2f(SC[y1c*136 + x1c]) : 0.f;
      r[j] = v00*(wy0*wx0) + v01*(wy0*wx1) + v10*(wy1*wx0) + v11*(wy1*wx1);
    }
    f32x4 r0 = {r[0],r[1],r[2],r[3]};
    f32x4 r1 = {r[4],r[5],r[6],r[7]};
    *(f32x4*)(op + px)     = r0;
    *(f32x4*)(op + px + 4) = r1;
    ca = na; cb2 = nb;
  }
}

// ---------------------------------------------------------------------------
extern "C" void kernel_launch(void* const* d_in, const int* in_sizes, int n_in,
                              void* d_out, int out_size, void* d_ws, size_t ws_size,
                              hipStream_t stream){
  const float* x  = (const float*)d_in[0];
  const float* Ws = (const float*)d_in[1];
  const float* bs = (const float*)d_in[2];
  const float* Wx = (const float*)d_in[3];
  const float* bx = (const float*)d_in[4];
  const float* Wy = (const float*)d_in[5];
  const float* by = (const float*)d_in[6];
  float* out = (float*)d_out;
  ushort_t* ws  = (ushort_t*)d_ws;
  ushort_t*     score  = ws;                                   // 33.5 MB f16
  unsigned int* coords = (unsigned int*)(ws + 16777216);       // 67.1 MB u32
  ushort_t*     WpH    = ws + 50331648;                        // 221 KB
  unsigned int* WpC    = (unsigned int*)(ws + 50331648 + 110592); // 147 KB

  k_repack  <<<dim3(576),  256, 0, stream>>>(Ws, Wx, Wy, WpH, WpC);
  k_conv_all<<<dim3(4096), 256, 0, stream>>>(x, WpH, WpC, bs, bx, by, score, coords);
  k_sample  <<<dim3(1024), 256, 0, stream>>>(score, coords, out);
}